// Round 5
// baseline (134.528 us; speedup 1.0000x reference)
//
#include <hip/hip_runtime.h>

typedef unsigned short u16;
typedef unsigned int u32;
typedef short v8s __attribute__((ext_vector_type(8)));
typedef float v4f __attribute__((ext_vector_type(4)));

__device__ __forceinline__ float bflo(u32 d){union{u32 i;float f;}u;u.i=d<<16;return u.f;}
__device__ __forceinline__ float bfhi(u32 d){union{u32 i;float f;}u;u.i=d&0xffff0000u;return u.f;}
__device__ __forceinline__ u16 f2bfr(float f){union{float f;u32 i;}u;u.f=f;return (u16)((u.i+0x8000u)>>16);}
__device__ __forceinline__ u32 pk2bf(float a,float b){
    union{float f;u32 i;}ua,ub; ua.f=a; ub.f=b;
    return ((ua.i+0x8000u)>>16)|((ub.i+0x8000u)&0xffff0000u);
}
__device__ __forceinline__ v8s pack8(const float* w){
    union { uint4 u; v8s v; } c;
    c.u.x = pk2bf(w[0],w[1]); c.u.y = pk2bf(w[2],w[3]);
    c.u.z = pk2bf(w[4],w[5]); c.u.w = pk2bf(w[6],w[7]);
    return c.v;
}

// Flash S@Wh, one 16-row strip per wave. S weights from factored exponentials:
// w = adj * ( Ei*Ej >= 1 ? Ei*Ej : Fi*Fj ),  E=exp(e), F=exp(0.2e).
__device__ __forceinline__ void flash_att(
    int wv, int l15, int q4,
    const float* __restrict__ ADJ,
    const float* __restrict__ sEi, const float* __restrict__ sFi,
    const float* __restrict__ sEj, const float* __restrict__ sFj,
    const u16* __restrict__ sWhT,
    v4f acc[4], float* invD)
{
    const int r0 = 16*wv + l15;
    const float Ei = sEi[r0], Fi = sFi[r0];
    float D = 0.f;
    #pragma unroll
    for (int ct = 0; ct < 4; ++ct) acc[ct] = (v4f){0.f,0.f,0.f,0.f};

    for (int ks = 0; ks < 4; ++ks) {
        const int ko = ks*32 + q4*8;
        float w[8];
        #pragma unroll
        for (int half = 0; half < 2; ++half) {
            float4 E4 = *(const float4*)(sEj + ko + 4*half);
            float4 F4 = *(const float4*)(sFj + ko + 4*half);
            float4 a4 = *(const float4*)(ADJ + r0*128 + ko + 4*half);
            float Ev[4] = {E4.x,E4.y,E4.z,E4.w};
            float Fv[4] = {F4.x,F4.y,F4.z,F4.w};
            float av[4] = {a4.x,a4.y,a4.z,a4.w};
            #pragma unroll
            for (int k = 0; k < 4; ++k) {
                float p = Ei * Ev[k];
                float q = Fi * Fv[k];
                float s = (p >= 1.f) ? p : q;
                float ww = s * av[k];
                w[half*4 + k] = ww;
                D += ww;
            }
        }
        v8s A = pack8(w);
        #pragma unroll
        for (int ct = 0; ct < 4; ++ct) {
            v8s B = *(const v8s*)(sWhT + (16*ct + l15)*136 + ko);
            acc[ct] = __builtin_amdgcn_mfma_f32_16x16x32_bf16(A, B, acc[ct], 0,0,0);
        }
    }
    D += __shfl_xor(D, 16); D += __shfl_xor(D, 32);
    *invD = 1.f / D;
}

__global__ __launch_bounds__(512, 8) void graphmixer_kernel(
    const float* __restrict__ C,     // (1024,128)
    const float* __restrict__ ADJ,   // (128,128)
    const float* __restrict__ EMB,   // (128,8)
    const float* __restrict__ W1,    // (9,64)
    const float* __restrict__ A1,    // (128)
    const float* __restrict__ W2,    // (64,64)
    const float* __restrict__ A2,    // (128)
    const float* __restrict__ LN1G, const float* __restrict__ LN1B,
    const float* __restrict__ LN2G, const float* __restrict__ LN2B,
    const float* __restrict__ HGW,  const float* __restrict__ HGB,
    const float* __restrict__ MLP1W, const float* __restrict__ MLP1B,
    const float* __restrict__ MLP2W, const float* __restrict__ MLP2B,
    const float* __restrict__ HMW,  const float* __restrict__ HMB,
    const float* __restrict__ G1W,  const float* __restrict__ G1B,
    const float* __restrict__ G2W,  const float* __restrict__ G2B,
    float* __restrict__ OUT)
{
    const int b = blockIdx.x, t = threadIdx.x;
    const int lane = t & 63, wv = t >> 6;
    const int l15 = lane & 15, q4 = lane >> 4;

    __shared__ __align__(16) unsigned char smem[40464];
    u16*   sWhT = (u16*)(smem);            // [64][136] bf16 : Wh1T then Wh2T  (17408)
    u16*   sH1  = (u16*)(smem + 17408);    // [128][72] bf16                    (18432)
    float* sEi  = (float*)(smem + 35840);  // 128: exp(ei)
    float* sFi  = (float*)(smem + 36352);  // 128: exp(0.2 ei)
    float* sEj  = (float*)(smem + 36864);  // 128: exp(ej)
    float* sFj  = (float*)(smem + 37376);  // 128: exp(0.2 ej)
    // union region (2048B): v-arrays live until e2; colp lives after P6
    float* v2i  = (float*)(smem + 37888);  // 64
    float* v2j  = (float*)(smem + 38144);  // 64
    float* v1i  = (float*)(smem + 38400);  // 9 (pad)
    float* v1j  = (float*)(smem + 38464);  // 9 (pad)
    float* colp = (float*)(smem + 37888);  // 8*64 (aliases v-arrays)
    float* sScr = (float*)(smem + 39936);  // 132
    // aliases in the sH1 region (dead until P4 epilogue):
    float* sEmb = (float*)(smem + 17408);  // 1024 f32
    float* sC   = (float*)(smem + 21504);  // 128 f32

    const float* Cb = C + b*128;

    // ================= P0 =================
    if (wv == 0) {
        #pragma unroll
        for (int q = 0; q < 4; ++q)
            ((float4*)sEmb)[lane + 64*q] = ((const float4*)EMB)[lane + 64*q];
        if (lane < 32) ((float4*)sC)[lane] = ((const float4*)Cb)[lane];
    } else if (wv == 1) {                         // q_mlp head (wave-private)
        float a = 0.f;
        for (int k = 0; k < 128; k += 4) {
            float4 c4 = *(const float4*)(Cb + k);
            a += c4.x*MLP1W[k*64+lane] + c4.y*MLP1W[(k+1)*64+lane]
               + c4.z*MLP1W[(k+2)*64+lane] + c4.w*MLP1W[(k+3)*64+lane];
        }
        sScr[lane] = fmaxf(a + MLP1B[lane], 0.f);
        float a2 = 0.f;
        for (int k = 0; k < 64; ++k) a2 += sScr[k] * MLP2W[k*64 + lane];
        float x2 = fmaxf(a2 + MLP2B[lane], 0.f);
        float p1 = x2 * HMW[lane];
        #pragma unroll
        for (int off = 32; off >= 1; off >>= 1) p1 += __shfl_down(p1, off);
        if (lane == 0) sScr[128] = p1 + HMB[0];
    } else if (wv == 2) {                         // gate head (wave-private)
        float a = 0.f;
        for (int k = 0; k < 128; k += 4) {
            float4 c4 = *(const float4*)(Cb + k);
            a += c4.x*G1W[k*64+lane] + c4.y*G1W[(k+1)*64+lane]
               + c4.z*G1W[(k+2)*64+lane] + c4.w*G1W[(k+3)*64+lane];
        }
        float g1 = fmaxf(a + G1B[lane], 0.f);
        float p2 = g1 * G2W[lane];
        #pragma unroll
        for (int off = 32; off >= 1; off >>= 1) p2 += __shfl_down(p2, off);
        if (lane == 0) sScr[129] = 1.f / (1.f + __expf(-(p2 + G2B[0])));
    } else if (wv == 3) {                         // v2i/v2j[k] = W2[k][:] . a2_{i,j}
        float ai = 0.f, aj = 0.f;
        for (int q = 0; q < 16; ++q) {
            float4 w  = *(const float4*)(W2 + lane*64 + q*4);
            float4 xi = *(const float4*)(A2 + q*4);
            float4 xj = *(const float4*)(A2 + 64 + q*4);
            ai += w.x*xi.x + w.y*xi.y + w.z*xi.z + w.w*xi.w;
            aj += w.x*xj.x + w.y*xj.y + w.z*xj.z + w.w*xj.w;
        }
        v2i[lane] = ai; v2j[lane] = aj;
    } else if (wv == 4) {                         // v1i/v1j
        if (lane < 9) {
            float a = 0.f;
            for (int q = 0; q < 16; ++q) {
                float4 w = *(const float4*)(W1 + lane*64 + q*4);
                float4 x = *(const float4*)(A1 + q*4);
                a += w.x*x.x + w.y*x.y + w.z*x.z + w.w*x.w;
            }
            v1i[lane] = a;
        } else if (lane >= 16 && lane < 25) {
            int f = lane - 16; float a = 0.f;
            for (int q = 0; q < 16; ++q) {
                float4 w = *(const float4*)(W1 + f*64 + q*4);
                float4 x = *(const float4*)(A1 + 64 + q*4);
                a += w.x*x.x + w.y*x.y + w.z*x.z + w.w*x.w;
            }
            v1j[f] = a;
        }
    }
    __syncthreads();   // b1

    // ================= P1: Wh1T (16 rows per wave) + e1 exp-vectors =================
    {
        const int o = lane;
        float w1f[9];
        #pragma unroll
        for (int f = 0; f < 9; ++f) w1f[f] = W1[f*64 + o];
        float whv[16];
        for (int ii = 0; ii < 16; ++ii) {
            const int ig = 16*wv + ii;
            float a = sC[ig] * w1f[0];
            float4 e0 = *(const float4*)(sEmb + ig*8);
            float4 e1 = *(const float4*)(sEmb + ig*8 + 4);
            a += e0.x*w1f[1] + e0.y*w1f[2] + e0.z*w1f[3] + e0.w*w1f[4];
            a += e1.x*w1f[5] + e1.y*w1f[6] + e1.z*w1f[7] + e1.w*w1f[8];
            whv[ii] = a;
        }
        u32 p[8];
        #pragma unroll
        for (int q = 0; q < 8; ++q) p[q] = pk2bf(whv[2*q], whv[2*q+1]);
        uint4* dst = (uint4*)(sWhT + o*136 + 16*wv);
        dst[0] = ((uint4*)p)[0]; dst[1] = ((uint4*)p)[1];
    }
    if (t < 128) {
        float c = sC[t];
        float4 e0 = *(const float4*)(sEmb + t*8);
        float4 e1 = *(const float4*)(sEmb + t*8 + 4);
        float ei = c*v1i[0] + e0.x*v1i[1]+e0.y*v1i[2]+e0.z*v1i[3]+e0.w*v1i[4]
                            + e1.x*v1i[5]+e1.y*v1i[6]+e1.z*v1i[7]+e1.w*v1i[8];
        float ej = c*v1j[0] + e0.x*v1j[1]+e0.y*v1j[2]+e0.z*v1j[3]+e0.w*v1j[4]
                            + e1.x*v1j[5]+e1.y*v1j[6]+e1.z*v1j[7]+e1.w*v1j[8];
        sEi[t] = __expf(ei); sFi[t] = __expf(0.2f*ei);
        sEj[t] = __expf(ej); sFj[t] = __expf(0.2f*ej);
    }
    __syncthreads();   // b2

    // ================= P4: flash S1@Wh1 + (1/D, ELU, LN1) -> sH1 =================
    {
        v4f acc[4]; float invD;
        flash_att(wv, l15, q4, ADJ, sEi, sFi, sEj, sFj, sWhT, acc, &invD);

        float g4[4], b4[4];
        #pragma unroll
        for (int ct = 0; ct < 4; ++ct) { g4[ct] = LN1G[16*ct + l15]; b4[ct] = LN1B[16*ct + l15]; }
        #pragma unroll
        for (int reg = 0; reg < 4; ++reg) {
            const int row = 16*wv + 4*q4 + reg;
            const float rd = __shfl(invD, 4*q4 + reg);
            float x[4], s1 = 0.f, s2 = 0.f;
            #pragma unroll
            for (int ct = 0; ct < 4; ++ct) {
                float v = acc[ct][reg] * rd;
                v = (v > 0.f) ? v : (__expf(v) - 1.f);      // ELU
                x[ct] = v; s1 += v; s2 += v*v;
            }
            s1 += __shfl_xor(s1, 1); s2 += __shfl_xor(s2, 1);
            s1 += __shfl_xor(s1, 2); s2 += __shfl_xor(s2, 2);
            s1 += __shfl_xor(s1, 4); s2 += __shfl_xor(s2, 4);
            s1 += __shfl_xor(s1, 8); s2 += __shfl_xor(s2, 8);
            const float mean = s1 * (1.f/64.f);
            const float var  = s2 * (1.f/64.f) - mean*mean;
            const float rstd = rsqrtf(var + 1e-5f);
            #pragma unroll
            for (int ct = 0; ct < 4; ++ct) {
                float h = (x[ct] - mean) * rstd * g4[ct] + b4[ct];
                sH1[row*72 + 16*ct + l15] = f2bfr(h);
            }
        }
    }
    __syncthreads();   // b4

    // ================= e2 exp-vectors (t<128) | P6: Wh2 = h1@W2 -> sWhT =================
    if (t < 128) {
        float ei = 0.f, ej = 0.f;
        const u16* hrow = sH1 + t*72;
        for (int q = 0; q < 16; ++q) {
            uint2 d = *(const uint2*)(hrow + q*4);
            float h0 = bflo(d.x), h1v = bfhi(d.x), h2 = bflo(d.y), h3 = bfhi(d.y);
            ei += h0*v2i[q*4+0] + h1v*v2i[q*4+1] + h2*v2i[q*4+2] + h3*v2i[q*4+3];
            ej += h0*v2j[q*4+0] + h1v*v2j[q*4+1] + h2*v2j[q*4+2] + h3*v2j[q*4+3];
        }
        sEi[t] = __expf(ei); sFi[t] = __expf(0.2f*ei);
        sEj[t] = __expf(ej); sFj[t] = __expf(0.2f*ej);
    }
    {
        v4f acc2[4];
        #pragma unroll
        for (int ct = 0; ct < 4; ++ct) acc2[ct] = (v4f){0.f,0.f,0.f,0.f};
        #pragma unroll
        for (int ks = 0; ks < 2; ++ks) {
            const int kb = ks*32 + q4*8;
            v8s A = *(const v8s*)(sH1 + (16*wv + l15)*72 + kb);
            #pragma unroll
            for (int ct = 0; ct < 4; ++ct) {
                const float* wp = W2 + kb*64 + 16*ct + l15;
                float w8[8];
                #pragma unroll
                for (int j = 0; j < 8; ++j) w8[j] = wp[j*64];
                acc2[ct] = __builtin_amdgcn_mfma_f32_16x16x32_bf16(A, pack8(w8), acc2[ct], 0,0,0);
            }
        }
        const int rb = 16*wv + 4*q4;
        #pragma unroll
        for (int ct = 0; ct < 4; ++ct) {
            uint2 p;
            p.x = pk2bf(acc2[ct][0], acc2[ct][1]);
            p.y = pk2bf(acc2[ct][2], acc2[ct][3]);
            *(uint2*)(sWhT + (16*ct + l15)*136 + rb) = p;
        }
    }
    __syncthreads();   // b6

    // ================= P7: flash S2@Wh2 + (1/D, +h1 relu, LN2, colsum) =================
    {
        v4f acc[4]; float invD;
        flash_att(wv, l15, q4, ADJ, sEi, sFi, sEj, sFj, sWhT, acc, &invD);

        float g4[4], b4[4], colsum[4];
        #pragma unroll
        for (int ct = 0; ct < 4; ++ct) {
            g4[ct] = LN2G[16*ct + l15]; b4[ct] = LN2B[16*ct + l15]; colsum[ct] = 0.f;
        }
        #pragma unroll
        for (int reg = 0; reg < 4; ++reg) {
            const int row = 16*wv + 4*q4 + reg;
            const float rd = __shfl(invD, 4*q4 + reg);
            float x[4], s1 = 0.f, s2 = 0.f;
            #pragma unroll
            for (int ct = 0; ct < 4; ++ct) {
                float h1v = bflo((u32)sH1[row*72 + 16*ct + l15]);
                float v = fmaxf(acc[ct][reg] * rd + h1v, 0.f);
                x[ct] = v; s1 += v; s2 += v*v;
            }
            s1 += __shfl_xor(s1, 1); s2 += __shfl_xor(s2, 1);
            s1 += __shfl_xor(s1, 2); s2 += __shfl_xor(s2, 2);
            s1 += __shfl_xor(s1, 4); s2 += __shfl_xor(s2, 4);
            s1 += __shfl_xor(s1, 8); s2 += __shfl_xor(s2, 8);
            const float mean = s1 * (1.f/64.f);
            const float var  = s2 * (1.f/64.f) - mean*mean;
            const float rstd = rsqrtf(var + 1e-5f);
            #pragma unroll
            for (int ct = 0; ct < 4; ++ct)
                colsum[ct] += (x[ct] - mean) * rstd * g4[ct] + b4[ct];
        }
        #pragma unroll
        for (int ct = 0; ct < 4; ++ct) {
            colsum[ct] += __shfl_xor(colsum[ct], 16);
            colsum[ct] += __shfl_xor(colsum[ct], 32);
        }
        if (lane < 16) {
            #pragma unroll
            for (int ct = 0; ct < 4; ++ct) colp[wv*64 + ct*16 + lane] = colsum[ct];
        }
    }
    __syncthreads();   // b8

    // ================= final combine (wave 0) =================
    if (wv == 0) {
        float s = 0.f;
        #pragma unroll
        for (int w = 0; w < 8; ++w) s += colp[w*64 + lane];
        float p = s * (1.f/128.f) * HGW[lane];
        #pragma unroll
        for (int off = 32; off >= 1; off >>= 1) p += __shfl_down(p, off);
        if (lane == 0) OUT[b] = sScr[128] + sScr[129] * (p + HGB[0]);
    }
}

extern "C" void kernel_launch(void* const* d_in, const int* in_sizes, int n_in,
                              void* d_out, int out_size, void* d_ws, size_t ws_size,
                              hipStream_t stream) {
    (void)n_in; (void)out_size; (void)d_ws; (void)ws_size;
    const float* C     = (const float*)d_in[0];
    const float* ADJ   = (const float*)d_in[1];
    const float* EMB   = (const float*)d_in[2];
    const float* W1    = (const float*)d_in[3];
    const float* A1    = (const float*)d_in[4];
    const float* W2    = (const float*)d_in[5];
    const float* A2    = (const float*)d_in[6];
    const float* LN1G  = (const float*)d_in[7];
    const float* LN1B  = (const float*)d_in[8];
    const float* LN2G  = (const float*)d_in[9];
    const float* LN2B  = (const float*)d_in[10];
    const float* HGW   = (const float*)d_in[11];
    const float* HGB   = (const float*)d_in[12];
    const float* MLP1W = (const float*)d_in[13];
    const float* MLP1B = (const float*)d_in[14];
    const float* MLP2W = (const float*)d_in[15];
    const float* MLP2B = (const float*)d_in[16];
    const float* HMW   = (const float*)d_in[17];
    const float* HMB   = (const float*)d_in[18];
    const float* G1W   = (const float*)d_in[19];
    const float* G1B   = (const float*)d_in[20];
    const float* G2W   = (const float*)d_in[21];
    const float* G2B   = (const float*)d_in[22];

    const int B = in_sizes[0] / 128;  // 1024

    graphmixer_kernel<<<dim3(B), dim3(512), 0, stream>>>(
        C, ADJ, EMB, W1, A1, W2, A2, LN1G, LN1B, LN2G, LN2B,
        HGW, HGB, MLP1W, MLP1B, MLP2W, MLP2B, HMW, HMB,
        G1W, G1B, G2W, G2B, (float*)d_out);
}

// Round 6
// 128.215 us; speedup vs baseline: 1.0492x; 1.0492x over previous
//
#include <hip/hip_runtime.h>

typedef unsigned short u16;
typedef unsigned int u32;
typedef short v8s __attribute__((ext_vector_type(8)));
typedef float v4f __attribute__((ext_vector_type(4)));

__device__ __forceinline__ float bflo(u32 d){union{u32 i;float f;}u;u.i=d<<16;return u.f;}
__device__ __forceinline__ float bfhi(u32 d){union{u32 i;float f;}u;u.i=d&0xffff0000u;return u.f;}
__device__ __forceinline__ u16 f2bfr(float f){union{float f;u32 i;}u;u.f=f;return (u16)((u.i+0x8000u)>>16);}
__device__ __forceinline__ u32 pk2bf(float a,float b){
    union{float f;u32 i;}ua,ub; ua.f=a; ub.f=b;
    return ((ua.i+0x8000u)>>16)|((ub.i+0x8000u)&0xffff0000u);
}
__device__ __forceinline__ v8s pack8(const float* w){
    union { uint4 u; v8s v; } c;
    c.u.x = pk2bf(w[0],w[1]); c.u.y = pk2bf(w[2],w[3]);
    c.u.z = pk2bf(w[4],w[5]); c.u.w = pk2bf(w[6],w[7]);
    return c.v;
}

// Flash S@Wh, two 16-row strips per wave (rows 16wv+l15 and +64).
// S weights from factored exponentials (no transcendentals in the loop):
// w = adj * ( Ei*Ej >= 1 ? Ei*Ej : Fi*Fj ),  E=exp(e), F=exp(0.2e).
__device__ __forceinline__ void flash_att(
    int wv, int l15, int q4,
    const float* __restrict__ ADJ,
    const float* __restrict__ sEi, const float* __restrict__ sFi,
    const float* __restrict__ sEj, const float* __restrict__ sFj,
    const u16* __restrict__ sWhT,
    v4f acc[2][4], float invD[2])
{
    const int r0 = 16*wv + l15, r1 = r0 + 64;
    const float Ei0 = sEi[r0], Fi0 = sFi[r0];
    const float Ei1 = sEi[r1], Fi1 = sFi[r1];
    float D0 = 0.f, D1 = 0.f;
    #pragma unroll
    for (int s = 0; s < 2; ++s)
        #pragma unroll
        for (int ct = 0; ct < 4; ++ct) acc[s][ct] = (v4f){0.f,0.f,0.f,0.f};

    for (int ks = 0; ks < 4; ++ks) {
        const int ko = ks*32 + q4*8;
        float w0[8], w1[8];
        #pragma unroll
        for (int half = 0; half < 2; ++half) {
            float4 E4 = *(const float4*)(sEj + ko + 4*half);
            float4 F4 = *(const float4*)(sFj + ko + 4*half);
            float4 a0 = *(const float4*)(ADJ + r0*128 + ko + 4*half);
            float4 a1 = *(const float4*)(ADJ + r1*128 + ko + 4*half);
            float Ev[4] = {E4.x,E4.y,E4.z,E4.w};
            float Fv[4] = {F4.x,F4.y,F4.z,F4.w};
            float av0[4] = {a0.x,a0.y,a0.z,a0.w};
            float av1[4] = {a1.x,a1.y,a1.z,a1.w};
            #pragma unroll
            for (int k = 0; k < 4; ++k) {
                float p0 = Ei0 * Ev[k], q0 = Fi0 * Fv[k];
                float s0 = (p0 >= 1.f) ? p0 : q0;
                float x0 = s0 * av0[k];
                float p1 = Ei1 * Ev[k], q1 = Fi1 * Fv[k];
                float s1 = (p1 >= 1.f) ? p1 : q1;
                float x1 = s1 * av1[k];
                w0[half*4 + k] = x0; w1[half*4 + k] = x1;
                D0 += x0; D1 += x1;
            }
        }
        v8s A0 = pack8(w0), A1 = pack8(w1);
        #pragma unroll
        for (int ct = 0; ct < 4; ++ct) {
            v8s B = *(const v8s*)(sWhT + (16*ct + l15)*136 + ko);
            acc[0][ct] = __builtin_amdgcn_mfma_f32_16x16x32_bf16(A0, B, acc[0][ct], 0,0,0);
            acc[1][ct] = __builtin_amdgcn_mfma_f32_16x16x32_bf16(A1, B, acc[1][ct], 0,0,0);
        }
    }
    D0 += __shfl_xor(D0, 16); D0 += __shfl_xor(D0, 32);
    D1 += __shfl_xor(D1, 16); D1 += __shfl_xor(D1, 32);
    invD[0] = 1.f / D0; invD[1] = 1.f / D1;
}

__global__ __launch_bounds__(256, 4) void graphmixer_kernel(
    const float* __restrict__ C,     // (1024,128)
    const float* __restrict__ ADJ,   // (128,128)
    const float* __restrict__ EMB,   // (128,8)
    const float* __restrict__ W1,    // (9,64)
    const float* __restrict__ A1,    // (128)
    const float* __restrict__ W2,    // (64,64)
    const float* __restrict__ A2,    // (128)
    const float* __restrict__ LN1G, const float* __restrict__ LN1B,
    const float* __restrict__ LN2G, const float* __restrict__ LN2B,
    const float* __restrict__ HGW,  const float* __restrict__ HGB,
    const float* __restrict__ MLP1W, const float* __restrict__ MLP1B,
    const float* __restrict__ MLP2W, const float* __restrict__ MLP2B,
    const float* __restrict__ HMW,  const float* __restrict__ HMB,
    const float* __restrict__ G1W,  const float* __restrict__ G1B,
    const float* __restrict__ G2W,  const float* __restrict__ G2B,
    float* __restrict__ OUT)
{
    const int b = blockIdx.x, t = threadIdx.x;
    const int lane = t & 63, wv = t >> 6;
    const int l15 = lane & 15, q4 = lane >> 4;

    __shared__ __align__(16) unsigned char smem[40096];
    u16*   sWhT = (u16*)(smem);            // [64][136] bf16 : Wh1T then Wh2T  (17408)
    u16*   sH1  = (u16*)(smem + 17408);    // [128][72] bf16                    (18432)
    float* sEi  = (float*)(smem + 35840);  // 128: exp(ei)
    float* sFi  = (float*)(smem + 36352);  // 128: exp(0.2 ei)
    float* sEj  = (float*)(smem + 36864);  // 128: exp(ej)
    float* sFj  = (float*)(smem + 37376);  // 128: exp(0.2 ej)
    float* colp = (float*)(smem + 37888);  // 256
    float* sScr = (float*)(smem + 38912);  // 136
    float* v2i  = (float*)(smem + 39456);  // 64
    float* v2j  = (float*)(smem + 39712);  // 64
    float* v1i  = (float*)(smem + 39968);  // 9 (pad 16)
    float* v1j  = (float*)(smem + 40032);  // 9 (pad 16)
    // aliases in the sH1 region (dead until P4 epilogue):
    float* sEmb = (float*)(smem + 17408);  // 1024 f32
    float* sC   = (float*)(smem + 21504);  // 128 f32

    const float* Cb = C + b*128;

    // ================= P0 =================
    if (wv == 0) {
        #pragma unroll
        for (int q = 0; q < 4; ++q)
            ((float4*)sEmb)[lane + 64*q] = ((const float4*)EMB)[lane + 64*q];
        if (lane < 32) ((float4*)sC)[lane] = ((const float4*)Cb)[lane];
        if (lane >= 32 && lane < 41) {            // v1i[f] = W1[f][:] . a1_i
            int f = lane - 32; float a = 0.f;
            for (int q = 0; q < 16; ++q) {
                float4 w = *(const float4*)(W1 + f*64 + q*4);
                float4 x = *(const float4*)(A1 + q*4);
                a += w.x*x.x + w.y*x.y + w.z*x.z + w.w*x.w;
            }
            v1i[f] = a;
        } else if (lane >= 48 && lane < 57) {     // v1j
            int f = lane - 48; float a = 0.f;
            for (int q = 0; q < 16; ++q) {
                float4 w = *(const float4*)(W1 + f*64 + q*4);
                float4 x = *(const float4*)(A1 + 64 + q*4);
                a += w.x*x.x + w.y*x.y + w.z*x.z + w.w*x.w;
            }
            v1j[f] = a;
        }
    } else if (wv == 3) {                         // v2i/v2j[k] = W2[k][:] . a2_{i,j}
        float ai = 0.f, aj = 0.f;
        for (int q = 0; q < 16; ++q) {
            float4 w  = *(const float4*)(W2 + lane*64 + q*4);
            float4 xi = *(const float4*)(A2 + q*4);
            float4 xj = *(const float4*)(A2 + 64 + q*4);
            ai += w.x*xi.x + w.y*xi.y + w.z*xi.z + w.w*xi.w;
            aj += w.x*xj.x + w.y*xj.y + w.z*xj.z + w.w*xj.w;
        }
        v2i[lane] = ai; v2j[lane] = aj;
    } else if (wv == 1) {                         // q_mlp head (wave-private)
        float a = 0.f;
        for (int k = 0; k < 128; k += 4) {
            float4 c4 = *(const float4*)(Cb + k);
            a += c4.x*MLP1W[k*64+lane] + c4.y*MLP1W[(k+1)*64+lane]
               + c4.z*MLP1W[(k+2)*64+lane] + c4.w*MLP1W[(k+3)*64+lane];
        }
        sScr[lane] = fmaxf(a + MLP1B[lane], 0.f);
        float a2 = 0.f;
        for (int k = 0; k < 64; ++k) a2 += sScr[k] * MLP2W[k*64 + lane];
        float x2 = fmaxf(a2 + MLP2B[lane], 0.f);
        float p1 = x2 * HMW[lane];
        #pragma unroll
        for (int off = 32; off >= 1; off >>= 1) p1 += __shfl_down(p1, off);
        if (lane == 0) sScr[128] = p1 + HMB[0];
    } else {                                      // wv==2: gate head (wave-private)
        float a = 0.f;
        for (int k = 0; k < 128; k += 4) {
            float4 c4 = *(const float4*)(Cb + k);
            a += c4.x*G1W[k*64+lane] + c4.y*G1W[(k+1)*64+lane]
               + c4.z*G1W[(k+2)*64+lane] + c4.w*G1W[(k+3)*64+lane];
        }
        float g1 = fmaxf(a + G1B[lane], 0.f);
        float p2 = g1 * G2W[lane];
        #pragma unroll
        for (int off = 32; off >= 1; off >>= 1) p2 += __shfl_down(p2, off);
        if (lane == 0) sScr[129] = 1.f / (1.f + __expf(-(p2 + G2B[0])));
    }
    __syncthreads();   // b1

    // ================= P1: Wh1T + e1 exp-vectors =================
    {
        const int o = lane, cc = wv;
        float w1f[9];
        #pragma unroll
        for (int f = 0; f < 9; ++f) w1f[f] = W1[f*64 + o];
        float whv[32];
        for (int i = 0; i < 32; ++i) {
            const int ig = cc*32 + i;
            float a = sC[ig] * w1f[0];
            float4 e0 = *(const float4*)(sEmb + ig*8);
            float4 e1 = *(const float4*)(sEmb + ig*8 + 4);
            a += e0.x*w1f[1] + e0.y*w1f[2] + e0.z*w1f[3] + e0.w*w1f[4];
            a += e1.x*w1f[5] + e1.y*w1f[6] + e1.z*w1f[7] + e1.w*w1f[8];
            whv[i] = a;
        }
        u32 p[16];
        #pragma unroll
        for (int q = 0; q < 16; ++q) p[q] = pk2bf(whv[2*q], whv[2*q+1]);
        uint4* dst = (uint4*)(sWhT + o*136 + cc*32);
        dst[0] = ((uint4*)p)[0]; dst[1] = ((uint4*)p)[1];
        dst[2] = ((uint4*)p)[2]; dst[3] = ((uint4*)p)[3];
    }
    if (t < 128) {
        float c = sC[t];
        float4 e0 = *(const float4*)(sEmb + t*8);
        float4 e1 = *(const float4*)(sEmb + t*8 + 4);
        float ei = c*v1i[0] + e0.x*v1i[1]+e0.y*v1i[2]+e0.z*v1i[3]+e0.w*v1i[4]
                            + e1.x*v1i[5]+e1.y*v1i[6]+e1.z*v1i[7]+e1.w*v1i[8];
        float ej = c*v1j[0] + e0.x*v1j[1]+e0.y*v1j[2]+e0.z*v1j[3]+e0.w*v1j[4]
                            + e1.x*v1j[5]+e1.y*v1j[6]+e1.z*v1j[7]+e1.w*v1j[8];
        sEi[t] = __expf(ei); sFi[t] = __expf(0.2f*ei);
        sEj[t] = __expf(ej); sFj[t] = __expf(0.2f*ej);
    }
    __syncthreads();   // b2

    // ================= P4: flash S1@Wh1 + (1/D, ELU, LN1) -> sH1 =================
    {
        v4f acc[2][4]; float invD[2];
        flash_att(wv, l15, q4, ADJ, sEi, sFi, sEj, sFj, sWhT, acc, invD);

        float g4[4], b4[4];
        #pragma unroll
        for (int ct = 0; ct < 4; ++ct) { g4[ct] = LN1G[16*ct + l15]; b4[ct] = LN1B[16*ct + l15]; }
        #pragma unroll
        for (int s = 0; s < 2; ++s) {
            const int rbase = 16*(wv + 4*s) + 4*q4;
            #pragma unroll
            for (int reg = 0; reg < 4; ++reg) {
                const int row = rbase + reg;
                const float rd = __shfl(invD[s], 4*q4 + reg);
                float x[4], s1 = 0.f, s2 = 0.f;
                #pragma unroll
                for (int ct = 0; ct < 4; ++ct) {
                    float v = acc[s][ct][reg] * rd;
                    v = (v > 0.f) ? v : (__expf(v) - 1.f);      // ELU
                    x[ct] = v; s1 += v; s2 += v*v;
                }
                s1 += __shfl_xor(s1, 1); s2 += __shfl_xor(s2, 1);
                s1 += __shfl_xor(s1, 2); s2 += __shfl_xor(s2, 2);
                s1 += __shfl_xor(s1, 4); s2 += __shfl_xor(s2, 4);
                s1 += __shfl_xor(s1, 8); s2 += __shfl_xor(s2, 8);
                const float mean = s1 * (1.f/64.f);
                const float var  = s2 * (1.f/64.f) - mean*mean;
                const float rstd = rsqrtf(var + 1e-5f);
                #pragma unroll
                for (int ct = 0; ct < 4; ++ct) {
                    float h = (x[ct] - mean) * rstd * g4[ct] + b4[ct];
                    sH1[row*72 + 16*ct + l15] = f2bfr(h);
                }
            }
        }
    }
    __syncthreads();   // b4

    // ================= e2 exp-vectors (t<128) | P6: Wh2 = h1@W2 -> sWhT =================
    if (t < 128) {
        float ei = 0.f, ej = 0.f;
        const u16* hrow = sH1 + t*72;
        for (int q = 0; q < 16; ++q) {
            uint2 d = *(const uint2*)(hrow + q*4);
            float h0 = bflo(d.x), h1v = bfhi(d.x), h2 = bflo(d.y), h3 = bfhi(d.y);
            ei += h0*v2i[q*4+0] + h1v*v2i[q*4+1] + h2*v2i[q*4+2] + h3*v2i[q*4+3];
            ej += h0*v2j[q*4+0] + h1v*v2j[q*4+1] + h2*v2j[q*4+2] + h3*v2j[q*4+3];
        }
        sEi[t] = __expf(ei); sFi[t] = __expf(0.2f*ei);
        sEj[t] = __expf(ej); sFj[t] = __expf(0.2f*ej);
    }
    {
        v4f acc2[2][4];
        #pragma unroll
        for (int s = 0; s < 2; ++s)
            #pragma unroll
            for (int ct = 0; ct < 4; ++ct) acc2[s][ct] = (v4f){0.f,0.f,0.f,0.f};
        #pragma unroll
        for (int ks = 0; ks < 2; ++ks) {
            const int kb = ks*32 + q4*8;
            v8s Bf[4];
            #pragma unroll
            for (int ct = 0; ct < 4; ++ct) {
                const float* wp = W2 + kb*64 + 16*ct + l15;
                float w8[8];
                #pragma unroll
                for (int j = 0; j < 8; ++j) w8[j] = wp[j*64];
                Bf[ct] = pack8(w8);
            }
            #pragma unroll
            for (int s = 0; s < 2; ++s) {
                v8s A = *(const v8s*)(sH1 + (16*(wv+4*s) + l15)*72 + kb);
                #pragma unroll
                for (int ct = 0; ct < 4; ++ct)
                    acc2[s][ct] = __builtin_amdgcn_mfma_f32_16x16x32_bf16(A, Bf[ct], acc2[s][ct], 0,0,0);
            }
        }
        #pragma unroll
        for (int s = 0; s < 2; ++s) {
            const int rb = 16*(wv+4*s) + 4*q4;
            #pragma unroll
            for (int ct = 0; ct < 4; ++ct) {
                const int col = 16*ct + l15;
                uint2 p;
                p.x = pk2bf(acc2[s][ct][0], acc2[s][ct][1]);
                p.y = pk2bf(acc2[s][ct][2], acc2[s][ct][3]);
                *(uint2*)(sWhT + col*136 + rb) = p;
            }
        }
    }
    __syncthreads();   // b6

    // ================= P7: flash S2@Wh2 + (1/D, +h1 relu, LN2, colsum) =================
    {
        v4f acc[2][4]; float invD[2];
        flash_att(wv, l15, q4, ADJ, sEi, sFi, sEj, sFj, sWhT, acc, invD);

        float g4[4], b4[4], colsum[4];
        #pragma unroll
        for (int ct = 0; ct < 4; ++ct) {
            g4[ct] = LN2G[16*ct + l15]; b4[ct] = LN2B[16*ct + l15]; colsum[ct] = 0.f;
        }
        #pragma unroll
        for (int s = 0; s < 2; ++s) {
            const int rbase = 16*(wv + 4*s) + 4*q4;
            #pragma unroll
            for (int reg = 0; reg < 4; ++reg) {
                const int row = rbase + reg;
                const float rd = __shfl(invD[s], 4*q4 + reg);
                float x[4], s1 = 0.f, s2 = 0.f;
                #pragma unroll
                for (int ct = 0; ct < 4; ++ct) {
                    float h1v = bflo((u32)sH1[row*72 + 16*ct + l15]);
                    float v = fmaxf(acc[s][ct][reg] * rd + h1v, 0.f);
                    x[ct] = v; s1 += v; s2 += v*v;
                }
                s1 += __shfl_xor(s1, 1); s2 += __shfl_xor(s2, 1);
                s1 += __shfl_xor(s1, 2); s2 += __shfl_xor(s2, 2);
                s1 += __shfl_xor(s1, 4); s2 += __shfl_xor(s2, 4);
                s1 += __shfl_xor(s1, 8); s2 += __shfl_xor(s2, 8);
                const float mean = s1 * (1.f/64.f);
                const float var  = s2 * (1.f/64.f) - mean*mean;
                const float rstd = rsqrtf(var + 1e-5f);
                #pragma unroll
                for (int ct = 0; ct < 4; ++ct)
                    colsum[ct] += (x[ct] - mean) * rstd * g4[ct] + b4[ct];
            }
        }
        #pragma unroll
        for (int ct = 0; ct < 4; ++ct) {
            colsum[ct] += __shfl_xor(colsum[ct], 16);
            colsum[ct] += __shfl_xor(colsum[ct], 32);
        }
        if (lane < 16) {
            #pragma unroll
            for (int ct = 0; ct < 4; ++ct) colp[wv*64 + ct*16 + lane] = colsum[ct];
        }
    }
    __syncthreads();   // b8

    // ================= final combine (wave 0) =================
    if (wv == 0) {
        float s = colp[lane] + colp[64 + lane] + colp[128 + lane] + colp[192 + lane];
        float p = s * (1.f/128.f) * HGW[lane];
        #pragma unroll
        for (int off = 32; off >= 1; off >>= 1) p += __shfl_down(p, off);
        if (lane == 0) OUT[b] = sScr[128] + sScr[129] * (p + HGB[0]);
    }
}

extern "C" void kernel_launch(void* const* d_in, const int* in_sizes, int n_in,
                              void* d_out, int out_size, void* d_ws, size_t ws_size,
                              hipStream_t stream) {
    (void)n_in; (void)out_size; (void)d_ws; (void)ws_size;
    const float* C     = (const float*)d_in[0];
    const float* ADJ   = (const float*)d_in[1];
    const float* EMB   = (const float*)d_in[2];
    const float* W1    = (const float*)d_in[3];
    const float* A1    = (const float*)d_in[4];
    const float* W2    = (const float*)d_in[5];
    const float* A2    = (const float*)d_in[6];
    const float* LN1G  = (const float*)d_in[7];
    const float* LN1B  = (const float*)d_in[8];
    const float* LN2G  = (const float*)d_in[9];
    const float* LN2B  = (const float*)d_in[10];
    const float* HGW   = (const float*)d_in[11];
    const float* HGB   = (const float*)d_in[12];
    const float* MLP1W = (const float*)d_in[13];
    const float* MLP1B = (const float*)d_in[14];
    const float* MLP2W = (const float*)d_in[15];
    const float* MLP2B = (const float*)d_in[16];
    const float* HMW   = (const float*)d_in[17];
    const float* HMB   = (const float*)d_in[18];
    const float* G1W   = (const float*)d_in[19];
    const float* G1B   = (const float*)d_in[20];
    const float* G2W   = (const float*)d_in[21];
    const float* G2B   = (const float*)d_in[22];

    const int B = in_sizes[0] / 128;  // 1024

    graphmixer_kernel<<<dim3(B), dim3(256), 0, stream>>>(
        C, ADJ, EMB, W1, A1, W2, A2, LN1G, LN1B, LN2G, LN2B,
        HGW, HGB, MLP1W, MLP1B, MLP2W, MLP2B, HMW, HMB,
        G1W, G1B, G2W, G2B, (float*)d_out);
}